// Round 14
// baseline (1082.368 us; speedup 1.0000x reference)
//
#include <hip/hip_runtime.h>
#include <hip/hip_bf16.h>

// Problem constants
#define NB    65536      // batch rows
#define KDIM  1024       // reduction dim for all projections
#define NDIM  1024       // output dim per projection

#define BK 32
#define NT (KDIM / BK)   // 32 K-tiles

typedef float f32x4  __attribute__((ext_vector_type(4)));
typedef short short8 __attribute__((ext_vector_type(8)));
typedef unsigned short ushort8v __attribute__((ext_vector_type(8)));

static __device__ __forceinline__ unsigned short f2bf(float f) {
    union { float f; unsigned u; } v; v.f = f;
    unsigned r = v.u + 0x7FFFu + ((v.u >> 16) & 1u);
    return (unsigned short)(r >> 16);
}
static __device__ __forceinline__ float bf2f(unsigned short h) {
    union { unsigned u; float f; } v; v.u = ((unsigned)h) << 16;
    return v.f;
}

// ---------------------------------------------------------------------------
// PACKED LAYOUT (GEMM-consumption order; r10: cold 64B-scatter caps at
// 1.98 TB/s; r11: packing -> streaming fetch):
//   1KB chunk index = ((r>>8)*32 + t)*16 + ((r>>4)&15)
//   inner (shorts)  = kc*128 + (r&15)*8 + pos
// A chunk read at lane*16B IS a complete 16-row x 32-k MFMA fragment set
// (row = lane&15, k-off = (lane>>4)*8) -- this makes DIRECT global->register
// operand streaming possible (no LDS rearrange needed).
// ---------------------------------------------------------------------------

// fp32 row-major [nrows][1024] -> packed bf16. One 16-row f-stripe per block.
__global__ __launch_bounds__(256) void pack_f32_k(
    const float* __restrict__ src, unsigned short* __restrict__ dst)
{
    const int tid = threadIdx.x;
    const int r   = blockIdx.x * 16 + (tid >> 4);   // global row
    const int cb  = (tid & 15) * 64;                // 64 cols per thread
    const int p   = r >> 8;
    const int f   = (r >> 4) & 15;
    const int rl  = r & 15;
    const float* s = src + (size_t)r * 1024 + cb;
#pragma unroll
    for (int g = 0; g < 8; ++g) {
        float4 va = *reinterpret_cast<const float4*>(s + g * 8);
        float4 vb = *reinterpret_cast<const float4*>(s + g * 8 + 4);
        ushort8v o;
        o[0] = f2bf(va.x); o[1] = f2bf(va.y); o[2] = f2bf(va.z); o[3] = f2bf(va.w);
        o[4] = f2bf(vb.x); o[5] = f2bf(vb.y); o[6] = f2bf(vb.z); o[7] = f2bf(vb.w);
        const int c0 = cb + g * 8;
        const int t  = c0 >> 5;
        const int kc = (c0 & 31) >> 3;
        *reinterpret_cast<ushort8v*>(
            &dst[((size_t)(p * 32 + t) * 16 + f) * 512 + kc * 128 + rl * 8]) = o;
    }
}

// ---------------------------------------------------------------------------
// REGISTER-STREAMING GEMM (AITER-flatmm-style, plain HIP): NO LDS, NO
// barriers in the K-loop. Packed operands are loaded straight into MFMA
// fragment registers (global short8 load = one fragment); compiler inserts
// precise counted vmcnt for register deps (its documented strength, m97),
// unlike the LDS-DMA path where it must drain at barriers.
//
// THEORY (r12/r13 arithmetic): LDS-staged variants serialize the LDS burst
// (~1400 cyc/256^2-tile) with the MFMA burst (~1240) -> observed ~2700
// cyc/tile across ALL schedule/occupancy variants. Removing LDS from the
// loop moves operand delivery to the VMEM/L2 pipe, which overlaps with
// MFMA via register scoreboarding.
//
// 256 thr = 4 independent waves (2 wm x 2 wn), block tile 256x128,
// per-wave output 128x64 (acc 8x4 f32x4 = 128 VGPR). Double-buffered
// operand sets (named arrays, rule #20). L2 traffic ~32x A amplification
// is absorbed by L1 (wn pairs) + XCD-local L2 (hot A panel = 512 KB).
// LDS (17.4 KB) only for the epilogue bounce -> full-line stores.
// ---------------------------------------------------------------------------
template<int OUT_F32, int NN>
__global__ __launch_bounds__(256, 2) void gemm_rs(
    const unsigned short* __restrict__ Ap, const unsigned short* __restrict__ Wp,
    const float* __restrict__ bias, void* __restrict__ Cptr)
{
    constexpr int GN = NN / 128;             // col tiles (8 or 16)
    __shared__ alignas(16) unsigned short bounce[64 * 136];   // 17.4 KB

    const int t    = threadIdx.x;
    const int lane = t & 63;
    const int wid  = t >> 6;                 // 0..3
    const int wm   = wid >> 1;               // 0..1  (128 rows each)
    const int wn   = wid & 1;                // 0..1  (64 cols each)

    // XCD-chunked swizzle (nwg % 8 == 0); bn0 fastest -> A panel hot per L2
    const int nwg  = gridDim.x;
    const int cpx  = nwg >> 3;
    const int orig = blockIdx.x;
    const int wgid = (orig & 7) * cpx + (orig >> 3);
    const int bn0  = (wgid & (GN - 1)) * 128;
    const int bm0  = (wgid / GN) * 256;

    const int pA  = bm0 >> 8;
    const int pB  = bn0 >> 8;  const int f0B = (bn0 >> 4) & 15;

    // per-wave stream bases: chunk stride 512 shorts, tile stride 8192 shorts
    const unsigned short* baseA = Ap + ((size_t)pA * 32 * 16 + wm * 8) * 512 + lane * 8;
    const unsigned short* baseB = Wp + ((size_t)pB * 32 * 16 + f0B + wn * 4) * 512 + lane * 8;

#define LOADT_(T, AA, BB) do {                                                  \
        _Pragma("unroll")                                                       \
        for (int _mi = 0; _mi < 8; ++_mi)                                       \
            AA[_mi] = *reinterpret_cast<const short8*>(                         \
                baseA + (size_t)(T) * 8192 + _mi * 512);                        \
        _Pragma("unroll")                                                       \
        for (int _ni = 0; _ni < 4; ++_ni)                                       \
            BB[_ni] = *reinterpret_cast<const short8*>(                         \
                baseB + (size_t)(T) * 8192 + _ni * 512);                        \
    } while (0)

#define MFMA_(AA, BB) do {                                                      \
        __builtin_amdgcn_s_setprio(1);                                          \
        _Pragma("unroll")                                                       \
        for (int _mi = 0; _mi < 8; ++_mi)                                       \
            _Pragma("unroll")                                                   \
            for (int _ni = 0; _ni < 4; ++_ni)                                   \
                acc[_mi][_ni] = __builtin_amdgcn_mfma_f32_16x16x32_bf16(        \
                    AA[_mi], BB[_ni], acc[_mi][_ni], 0, 0, 0);                  \
        __builtin_amdgcn_s_setprio(0);                                          \
    } while (0)

    f32x4 acc[8][4];
#pragma unroll
    for (int mi = 0; mi < 8; ++mi)
#pragma unroll
        for (int ni = 0; ni < 4; ++ni)
            acc[mi][ni] = (f32x4){0.f, 0.f, 0.f, 0.f};

    short8 a0[8], b0[4], a1[8], b1[4];
    LOADT_(0, a0, b0);

#pragma unroll 1
    for (int tt = 0; tt < NT; tt += 2) {
        LOADT_(tt + 1, a1, b1);              // tt+1 <= 31 always valid
        MFMA_(a0, b0);
        if (tt + 2 < NT) LOADT_(tt + 2, a0, b0);
        MFMA_(a1, b1);
    }

    // ---------------- epilogue: LDS bounce -> full-line stores --------------
    // acc fragment: D row = (lane>>4)*4 + r, col = lane&15  [m89-verified]
    const int crow = (lane >> 4) * 4;
    const int ccol = lane & 15;

    if (OUT_F32) {
        float* Cf  = (float*)Cptr;
        float* bbf = reinterpret_cast<float*>(&bounce[0]);
        float bv[4];
#pragma unroll
        for (int ni = 0; ni < 4; ++ni)
            bv[ni] = bias[bn0 + wn * 64 + ni * 16 + ccol];
        // 8 passes x 32 rows x 128 cols (stride 136 floats, 17.4 KB)
#pragma unroll
        for (int p = 0; p < 8; ++p) {
            if (wm == (p >> 2)) {
#pragma unroll
                for (int mlo = 0; mlo < 2; ++mlo) {
                    int ml = (p & 3) * 2 + mlo;
#pragma unroll
                    for (int ni = 0; ni < 4; ++ni)
#pragma unroll
                        for (int r = 0; r < 4; ++r)
                            bbf[(mlo * 16 + crow + r) * 136 + wn * 64 + ni * 16 + ccol]
                                = acc[ml][ni][r] + bv[ni];
                }
            }
            __syncthreads();
#pragma unroll
            for (int it = 0; it < 4; ++it) {
                int lrow = it * 8 + (t >> 5);            // 0..31
                int lcol = (t & 31) * 4;                 // 0..124
                f32x4 v = *reinterpret_cast<const f32x4*>(&bbf[lrow * 136 + lcol]);
                *reinterpret_cast<f32x4*>(
                    &Cf[(size_t)(bm0 + p * 32 + lrow) * NN + bn0 + lcol]) = v;
            }
            __syncthreads();
        }
    } else {
        unsigned short* Cb = (unsigned short*)Cptr;
        // 4 passes x 64 rows x 128 cols (stride 136 shorts, 17.4 KB)
#pragma unroll
        for (int p = 0; p < 4; ++p) {
            if (wm == (p >> 1)) {
#pragma unroll
                for (int mlj = 0; mlj < 4; ++mlj) {
                    int ml = (p & 1) * 4 + mlj;
#pragma unroll
                    for (int ni = 0; ni < 4; ++ni)
#pragma unroll
                        for (int r = 0; r < 4; ++r)
                            bounce[(mlj * 16 + crow + r) * 136 + wn * 64 + ni * 16 + ccol]
                                = f2bf(acc[ml][ni][r]);
                }
            }
            __syncthreads();
#pragma unroll
            for (int it = 0; it < 4; ++it) {
                int lrow = it * 16 + (t >> 4);           // 0..63
                int lcol = (t & 15) * 8;                 // 0..120
                ushort8v v = *reinterpret_cast<const ushort8v*>(&bounce[lrow * 136 + lcol]);
                *reinterpret_cast<ushort8v*>(
                    &Cb[(size_t)(bm0 + p * 64 + lrow) * NN + bn0 + lcol]) = v;
            }
            __syncthreads();
        }
    }
#undef LOADT_
#undef MFMA_
}

// ---------------------------------------------------------------------------
// Per-row attention, 16 rows/block (16 waves), wave-per-row body.
// Reads Q (row-major) + fused KV (row stride 2048); writes feats PACKED.
// ---------------------------------------------------------------------------
__global__ __launch_bounds__(1024) void attn_k(
    const unsigned short* __restrict__ Qb, const unsigned short* __restrict__ KVb,
    unsigned short* __restrict__ Fp)
{
    __shared__ alignas(16) unsigned short KL[16][1024];   // K rows; reused as feats
    __shared__ alignas(16) unsigned short VL[16][1024];
    const int t = threadIdx.x;
    const int lane = t & 63;
    const int wid = t >> 6;                       // 0..15
    const size_t row = (size_t)blockIdx.x * 16 + wid;
    const size_t base = row * 1024;
    const size_t bkv  = row * 2048;
    const int off = lane * 16;

    ushort8v q0 = *reinterpret_cast<const ushort8v*>(&Qb[base + off]);
    ushort8v q1 = *reinterpret_cast<const ushort8v*>(&Qb[base + off + 8]);
    float qf[16];
#pragma unroll
    for (int j = 0; j < 8; ++j) { qf[j] = bf2f(q0[j]); qf[8 + j] = bf2f(q1[j]); }

    *reinterpret_cast<ushort8v*>(&KL[wid][off])     = *reinterpret_cast<const ushort8v*>(&KVb[bkv + off]);
    *reinterpret_cast<ushort8v*>(&KL[wid][off + 8]) = *reinterpret_cast<const ushort8v*>(&KVb[bkv + off + 8]);
    *reinterpret_cast<ushort8v*>(&VL[wid][off])     = *reinterpret_cast<const ushort8v*>(&KVb[bkv + 1024 + off]);
    *reinterpret_cast<ushort8v*>(&VL[wid][off + 8]) = *reinterpret_cast<const ushort8v*>(&KVb[bkv + 1024 + off + 8]);
    __syncthreads();

    const int sub = lane & 3;
    float s[16];
#pragma unroll
    for (int g = 0; g < 16; ++g) {
        const ushort8v k0 = *reinterpret_cast<const ushort8v*>(&KL[wid][g * 64 + sub * 16]);
        const ushort8v k1 = *reinterpret_cast<const ushort8v*>(&KL[wid][g * 64 + sub * 16 + 8]);
        float acc = 0.f;
#pragma unroll
        for (int j = 0; j < 8; ++j)
            acc += qf[j] * bf2f(k0[j]) + qf[8 + j] * bf2f(k1[j]);
        s[g] = acc;
    }
#pragma unroll
    for (int m = 1; m <= 2; m <<= 1)
#pragma unroll
        for (int g = 0; g < 16; ++g)
            s[g] += __shfl_xor(s[g], m, 64);

    float mx = s[0];
#pragma unroll
    for (int g = 1; g < 16; ++g) mx = fmaxf(mx, s[g]);
    float p[16], denom = 0.f;
#pragma unroll
    for (int g = 0; g < 16; ++g) {
        p[g] = __expf((s[g] - mx) * 0.125f);
        denom += p[g];
    }
    float inv = 1.f / denom;

    float f[16];
#pragma unroll
    for (int j = 0; j < 16; ++j) f[j] = 0.f;
#pragma unroll
    for (int g = 0; g < 16; ++g) {
        float pg = p[g] * inv;
        const ushort8v v0 = *reinterpret_cast<const ushort8v*>(&VL[wid][g * 64 + sub * 16]);
        const ushort8v v1 = *reinterpret_cast<const ushort8v*>(&VL[wid][g * 64 + sub * 16 + 8]);
#pragma unroll
        for (int j = 0; j < 8; ++j) {
            f[j]     += pg * bf2f(v0[j]);
            f[8 + j] += pg * bf2f(v1[j]);
        }
    }
    ushort8v o0, o1;
#pragma unroll
    for (int j = 0; j < 8; ++j) { o0[j] = f2bf(f[j]); o1[j] = f2bf(f[8 + j]); }
    // stash row into feats LDS (= KL; own-wave region, own reads long done)
    *reinterpret_cast<ushort8v*>(&KL[wid][off])     = o0;
    *reinterpret_cast<ushort8v*>(&KL[wid][off + 8]) = o1;
    __syncthreads();

    // cooperative packed write: block = f-stripe (p, f); 32KB total
    const int r0 = blockIdx.x * 16;
    const int pp = r0 >> 8;
    const int ff = (r0 >> 4) & 15;
    const int tt = t >> 5;          // tile 0..31
    const int kc = (t >> 3) & 3;    // k-chunk 0..3
    const int rp = t & 7;           // row pair 0..7
    unsigned short* db = &Fp[((size_t)(pp * 32 + tt) * 16 + ff) * 512 + kc * 128 + rp * 16];
    *reinterpret_cast<ushort8v*>(db)     = *reinterpret_cast<const ushort8v*>(&KL[rp * 2][tt * 32 + kc * 8]);
    *reinterpret_cast<ushort8v*>(db + 8) = *reinterpret_cast<const ushort8v*>(&KL[rp * 2 + 1][tt * 32 + kc * 8]);
}

// ---------------------------------------------------------------------------
extern "C" void kernel_launch(void* const* d_in, const int* in_sizes, int n_in,
                              void* d_out, int out_size, void* d_ws, size_t ws_size,
                              hipStream_t stream)
{
    (void)in_sizes; (void)n_in; (void)out_size; (void)ws_size;
    const float* latent = (const float*)d_in[0];
    const float* cond   = (const float*)d_in[1];
    const float* Wq     = (const float*)d_in[2];
    const float* Wk     = (const float*)d_in[3];
    const float* Wv     = (const float*)d_in[4];
    const float* Wout   = (const float*)d_in[5];
    const float* bout   = (const float*)d_in[6];
    float* out = (float*)d_out;

    char* ws = (char*)d_ws;
    const size_t MB = 1ull << 20;
    unsigned short* wqp  = (unsigned short*)(ws + 0 * MB);    // 2 MB packed Wq
    unsigned short* wkvp = (unsigned short*)(ws + 2 * MB);    // 4 MB packed [Wk;Wv]
    unsigned short* wop  = (unsigned short*)(ws + 6 * MB);    // 2 MB packed Wout
    unsigned short* Qb   = (unsigned short*)(ws + 8 * MB);    // 128 MB row-major Q
    unsigned short* KVb  = (unsigned short*)(ws + 136 * MB);  // 256 MB row-major fused K|V
    unsigned short* Lp   = (unsigned short*)(ws + 392 * MB);  // 128 MB packed latent; reused as packed feats
    unsigned short* Cp   = (unsigned short*)(ws + 520 * MB);  // 128 MB packed cond
    unsigned short* Fp   = Lp;                                // Lp dead after GEMM-Q

    // weight packs (tiny)
    pack_f32_k<<<NDIM / 16, 256, 0, stream>>>(Wq,   wqp);
    pack_f32_k<<<NDIM / 16, 256, 0, stream>>>(Wk,   wkvp);
    pack_f32_k<<<NDIM / 16, 256, 0, stream>>>(Wv,   wkvp + 1048576);  // panels 4..7
    pack_f32_k<<<NDIM / 16, 256, 0, stream>>>(Wout, wop);

    // activation packs (fp32 -> packed bf16)
    pack_f32_k<<<NB / 16, 256, 0, stream>>>(latent, Lp);
    pack_f32_k<<<NB / 16, 256, 0, stream>>>(cond,   Cp);

    // Q projection (N=1024) and fused K|V projection (N=2048, W stacked)
    gemm_rs<0, 1024><<<(NB / 256) * (1024 / 128), 256, 0, stream>>>(Lp, wqp,  nullptr, Qb);
    gemm_rs<0, 2048><<<(NB / 256) * (2048 / 128), 256, 0, stream>>>(Cp, wkvp, nullptr, KVb);

    // attention: row-major Q/KV in, PACKED feats out (into Fp = Lp)
    attn_k<<<NB / 16, 1024, 0, stream>>>(Qb, KVb, Fp);

    // output projection reads packed feats
    gemm_rs<1, 1024><<<(NB / 256) * (1024 / 128), 256, 0, stream>>>(Fp, wop, bout, out);
}

// Round 15
// 967.663 us; speedup vs baseline: 1.1185x; 1.1185x over previous
//
#include <hip/hip_runtime.h>
#include <hip/hip_bf16.h>

// Problem constants
#define NB    65536      // batch rows
#define KDIM  1024       // reduction dim for all projections
#define NDIM  1024       // output dim per projection

#define BK 32
#define NT (KDIM / BK)   // 32 K-tiles

typedef float f32x4  __attribute__((ext_vector_type(4)));
typedef short short8 __attribute__((ext_vector_type(8)));
typedef unsigned short ushort8v __attribute__((ext_vector_type(8)));

static __device__ __forceinline__ unsigned short f2bf(float f) {
    union { float f; unsigned u; } v; v.f = f;
    unsigned r = v.u + 0x7FFFu + ((v.u >> 16) & 1u);
    return (unsigned short)(r >> 16);
}
static __device__ __forceinline__ float bf2f(unsigned short h) {
    union { unsigned u; float f; } v; v.u = ((unsigned)h) << 16;
    return v.f;
}

// async global->LDS, 16B per lane. LDS dest = wave-uniform base + lane*16.
static __device__ __forceinline__ void gload16(const unsigned short* g, unsigned short* l) {
    __builtin_amdgcn_global_load_lds(
        (const __attribute__((address_space(1))) unsigned int*)g,
        (__attribute__((address_space(3))) unsigned int*)l, 16, 0, 0);
}

// ---------------------------------------------------------------------------
// PACKED LAYOUT (GEMM-consumption order; r10: cold 64B-scatter caps at
// 1.98 TB/s; r11: packing -> 900 TF streaming):
//   1KB chunk index = ((r>>8)*32 + t)*16 + ((r>>4)&15)
//   inner (shorts)  = kc*128 + (r&15)*8 + pos
// ---------------------------------------------------------------------------

// ONE pack dispatch for all 6 fp32->packed-bf16 conversions (r12 had 6
// dispatches; ~10 us launch/tail overhead each). Segment decode on blockIdx.
__global__ __launch_bounds__(256) void pack_all_k(
    const float* __restrict__ latent, const float* __restrict__ cond,
    const float* __restrict__ Wq, const float* __restrict__ Wk,
    const float* __restrict__ Wv, const float* __restrict__ Wout,
    unsigned short* __restrict__ Lp, unsigned short* __restrict__ Cp,
    unsigned short* __restrict__ wqp, unsigned short* __restrict__ wkvp,
    unsigned short* __restrict__ wop)
{
    const int b = blockIdx.x;
    const float* src; unsigned short* dst; int rb;
    if (b < 4096)      { src = latent; dst = Lp;              rb = b; }
    else if (b < 8192) { src = cond;   dst = Cp;              rb = b - 4096; }
    else if (b < 8256) { src = Wq;     dst = wqp;             rb = b - 8192; }
    else if (b < 8320) { src = Wk;     dst = wkvp;            rb = b - 8256; }
    else if (b < 8384) { src = Wv;     dst = wkvp + 1048576;  rb = b - 8320; }
    else               { src = Wout;   dst = wop;             rb = b - 8384; }

    const int tid = threadIdx.x;
    const int r   = rb * 16 + (tid >> 4);           // row within segment
    const int cb  = (tid & 15) * 64;                // 64 cols per thread
    const int p   = r >> 8;
    const int f   = (r >> 4) & 15;
    const int rl  = r & 15;
    const float* s = src + (size_t)r * 1024 + cb;
#pragma unroll
    for (int g = 0; g < 8; ++g) {
        float4 va = *reinterpret_cast<const float4*>(s + g * 8);
        float4 vb = *reinterpret_cast<const float4*>(s + g * 8 + 4);
        ushort8v o;
        o[0] = f2bf(va.x); o[1] = f2bf(va.y); o[2] = f2bf(va.z); o[3] = f2bf(va.w);
        o[4] = f2bf(vb.x); o[5] = f2bf(vb.y); o[6] = f2bf(vb.z); o[7] = f2bf(vb.w);
        const int c0 = cb + g * 8;
        const int t  = c0 >> 5;
        const int kc = (c0 & 31) >> 3;
        *reinterpret_cast<ushort8v*>(
            &dst[((size_t)(p * 32 + t) * 16 + f) * 512 + kc * 128 + rl * 8]) = o;
    }
}

// ---------------------------------------------------------------------------
// r12-verified 256x256 GEMM core (2-phase, ring-4, packed operands, counted
// vmcnt(8) once per tile -- measured 300 us / ~915 TF on the KV shape, the
// plain-HIP structural plateau; r13/r14 alternatives regressed).
// 512 thr = 8 waves (2 Mw x 4 Nw), per-wave output 128x64.
// ---------------------------------------------------------------------------
typedef unsigned short ldsT[4][2][16][512];

static __device__ __forceinline__ void gemm_core(
    const unsigned short* __restrict__ Ap, const unsigned short* __restrict__ Wp,
    int pA, int pB, int lane, int wid, int wm, int wn,
    ldsT& lds, f32x4 (&acc)[8][4])
{
#define STAGE1_(TAU, SLOT, AB) do {                                             \
        int _tc = (TAU) < NT ? (TAU) : NT - 1;                                  \
        const unsigned short* _b = (AB) ? Wp : Ap;                              \
        int _pp = (AB) ? pB : pA;                                               \
        _Pragma("unroll")                                                       \
        for (int _j = 0; _j < 2; ++_j) {                                        \
            int _f = wid * 2 + _j;                                              \
            gload16(_b + ((size_t)(_pp * 32 + _tc) * 16 + _f) * 512 + lane * 8, \
                    &lds[SLOT][AB][_f][0]);                                     \
        }                                                                       \
    } while (0)

#define LDA_(S, MI) \
    (*reinterpret_cast<const short8*>(&lds[S][0][wm * 8 + (MI)][lane * 8]))
#define LDB_(S, NI) \
    (*reinterpret_cast<const short8*>(&lds[S][1][wn * 4 + (NI)][lane * 8]))

    // prologue: stage tiles 0,1,2 (12 loads); validate tile 0 (vmcnt(8))
    STAGE1_(0, 0, 0); STAGE1_(0, 0, 1);
    STAGE1_(1, 1, 0); STAGE1_(1, 1, 1);
    STAGE1_(2, 2, 0); STAGE1_(2, 2, 1);
    asm volatile("s_waitcnt vmcnt(8)" ::: "memory");
    __builtin_amdgcn_s_barrier();

#pragma unroll 1
    for (int tt = 0; tt < NT; ++tt) {
        const int slot = tt & 3;
        short8 af0[4], af1[4], bq[4];

        // phase 1: af-lo + bq reads | stage A(t+3) | MFMA mi 0-3
#pragma unroll
        for (int mi = 0; mi < 4; ++mi) af0[mi] = LDA_(slot, mi);
#pragma unroll
        for (int ni = 0; ni < 4; ++ni) bq[ni] = LDB_(slot, ni);
        STAGE1_(tt + 3, (tt + 3) & 3, 0);
        __builtin_amdgcn_s_barrier();
        asm volatile("s_waitcnt lgkmcnt(0)" ::: "memory");
        __builtin_amdgcn_s_setprio(1);
#pragma unroll
        for (int mi = 0; mi < 4; ++mi)
#pragma unroll
            for (int ni = 0; ni < 4; ++ni)
                acc[mi][ni] = __builtin_amdgcn_mfma_f32_16x16x32_bf16(
                    af0[mi], bq[ni], acc[mi][ni], 0, 0, 0);
        __builtin_amdgcn_s_setprio(0);
        __builtin_amdgcn_s_barrier();

        // phase 2: af-hi reads | stage B(t+3) | vmcnt(8) | MFMA mi 4-7
#pragma unroll
        for (int mi = 0; mi < 4; ++mi) af1[mi] = LDA_(slot, 4 + mi);
        STAGE1_(tt + 3, (tt + 3) & 3, 1);
        asm volatile("s_waitcnt vmcnt(8)" ::: "memory");  // tile tt+1 landed
        __builtin_amdgcn_s_barrier();
        asm volatile("s_waitcnt lgkmcnt(0)" ::: "memory");
        __builtin_amdgcn_s_setprio(1);
#pragma unroll
        for (int mi = 0; mi < 4; ++mi)
#pragma unroll
            for (int ni = 0; ni < 4; ++ni)
                acc[4 + mi][ni] = __builtin_amdgcn_mfma_f32_16x16x32_bf16(
                    af1[mi], bq[ni], acc[4 + mi][ni], 0, 0, 0);
        __builtin_amdgcn_s_setprio(0);
        __builtin_amdgcn_s_barrier();
    }
    asm volatile("s_waitcnt vmcnt(0)" ::: "memory");
    __builtin_amdgcn_s_barrier();
#undef STAGE1_
#undef LDA_
#undef LDB_
}

// ---------------------------------------------------------------------------
// MERGED Q + KV projection GEMM: blocks [0,1024) = Q (Lp @ wqp -> Qb,
// NN=1024); blocks [1024,3072) = KV (Cp @ wkvp -> KVb, NN=2048). One
// dispatch removes the Q-tail drain-refill bubble. Swizzle over combined
// grid (3072 % 8 == 0, bijective).
// ---------------------------------------------------------------------------
__global__ __launch_bounds__(512, 2) void gemm_qkv(
    const unsigned short* __restrict__ Lp, const unsigned short* __restrict__ Cp,
    const unsigned short* __restrict__ wqp, const unsigned short* __restrict__ wkvp,
    unsigned short* __restrict__ Qb, unsigned short* __restrict__ KVb)
{
    __shared__ alignas(16) ldsT lds;

    const int t    = threadIdx.x;
    const int lane = t & 63;
    const int wid  = t >> 6;
    const int wm   = wid >> 2;
    const int wn   = wid & 3;

    const int nwg  = gridDim.x;              // 3072
    const int cpx  = nwg >> 3;               // 384
    const int orig = blockIdx.x;
    const int wgid = (orig & 7) * cpx + (orig >> 3);

    const unsigned short* Ap; const unsigned short* Wp;
    unsigned short* Cb; int NN, bn0, bm0;
    if (wgid < 1024) {                       // Q segment, GN=4
        Ap = Lp; Wp = wqp; Cb = Qb; NN = 1024;
        bn0 = (wgid & 3) * 256; bm0 = (wgid >> 2) * 256;
    } else {                                 // KV segment, GN=8
        int w2 = wgid - 1024;
        Ap = Cp; Wp = wkvp; Cb = KVb; NN = 2048;
        bn0 = (w2 & 7) * 256; bm0 = (w2 >> 3) * 256;
    }
    const int pA = bm0 >> 8, pB = bn0 >> 8;

    f32x4 acc[8][4];
#pragma unroll
    for (int mi = 0; mi < 8; ++mi)
#pragma unroll
        for (int ni = 0; ni < 4; ++ni)
            acc[mi][ni] = (f32x4){0.f, 0.f, 0.f, 0.f};

    gemm_core(Ap, Wp, pA, pB, lane, wid, wm, wn, lds, acc);

    // bf16 epilogue: LDS bounce -> full-line stores (r7+: WRITE exact-ideal)
    const int crow = (lane >> 4) * 4;
    const int ccol = lane & 15;
    unsigned short* bb = &lds[0][0][0][0];
#pragma unroll
    for (int p = 0; p < 2; ++p) {
        if (wm == p) {
#pragma unroll
            for (int ml = 0; ml < 8; ++ml)
#pragma unroll
                for (int ni = 0; ni < 4; ++ni)
#pragma unroll
                    for (int r = 0; r < 4; ++r)
                        bb[(ml * 16 + crow + r) * 264 + wn * 64 + ni * 16 + ccol]
                            = f2bf(acc[ml][ni][r]);
        }
        __syncthreads();
#pragma unroll
        for (int it = 0; it < 8; ++it) {
            int lrow = wid * 16 + it * 2 + (lane >> 5);
            int lcol = (lane & 31) * 8;
            ushort8v v = *reinterpret_cast<const ushort8v*>(&bb[lrow * 264 + lcol]);
            *reinterpret_cast<ushort8v*>(
                &Cb[(size_t)(bm0 + p * 128 + lrow) * NN + bn0 + lcol]) = v;
        }
        __syncthreads();
    }
}

// ---------------------------------------------------------------------------
// Output projection: packed feats @ packed Wout^T + bias -> fp32 out.
// ---------------------------------------------------------------------------
__global__ __launch_bounds__(512, 2) void gemm_out(
    const unsigned short* __restrict__ Fp, const unsigned short* __restrict__ wop,
    const float* __restrict__ bias, float* __restrict__ Cf)
{
    constexpr int NN = 1024;
    __shared__ alignas(16) ldsT lds;

    const int t    = threadIdx.x;
    const int lane = t & 63;
    const int wid  = t >> 6;
    const int wm   = wid >> 2;
    const int wn   = wid & 3;

    const int nwg  = gridDim.x;              // 1024
    const int cpx  = nwg >> 3;
    const int orig = blockIdx.x;
    const int wgid = (orig & 7) * cpx + (orig >> 3);
    const int bn0  = (wgid & 3) * 256;
    const int bm0  = (wgid >> 2) * 256;
    const int pA = bm0 >> 8, pB = bn0 >> 8;

    f32x4 acc[8][4];
#pragma unroll
    for (int mi = 0; mi < 8; ++mi)
#pragma unroll
        for (int ni = 0; ni < 4; ++ni)
            acc[mi][ni] = (f32x4){0.f, 0.f, 0.f, 0.f};

    gemm_core(Fp, wop, pA, pB, lane, wid, wm, wn, lds, acc);

    // fp32 epilogue with bias (r12 verbatim)
    const int crow = (lane >> 4) * 4;
    const int ccol = lane & 15;
    float* bbf = reinterpret_cast<float*>(&lds[0][0][0][0]);
    float bv[4];
#pragma unroll
    for (int ni = 0; ni < 4; ++ni)
        bv[ni] = bias[bn0 + wn * 64 + ni * 16 + ccol];
#pragma unroll
    for (int p = 0; p < 4; ++p) {
        if (wm == (p >> 1)) {
#pragma unroll
            for (int ml = 0; ml < 4; ++ml)
#pragma unroll
                for (int ni = 0; ni < 4; ++ni)
#pragma unroll
                    for (int r = 0; r < 4; ++r)
                        bbf[(ml * 16 + crow + r) * 268 + wn * 64 + ni * 16 + ccol]
                            = acc[(p & 1) * 4 + ml][ni][r] + bv[ni];
        }
        __syncthreads();
#pragma unroll
        for (int it = 0; it < 8; ++it) {
            int lrow = wid * 8 + it;
            f32x4 v = *reinterpret_cast<const f32x4*>(&bbf[lrow * 268 + lane * 4]);
            *reinterpret_cast<f32x4*>(
                &Cf[(size_t)(bm0 + p * 64 + lrow) * NN + bn0 + lane * 4]) = v;
        }
        __syncthreads();
    }
}

// ---------------------------------------------------------------------------
// Per-row attention, 16 rows/block (16 waves), wave-per-row body (r12
// verbatim). Reads Q row-major + fused KV (stride 2048); writes feats PACKED.
// ---------------------------------------------------------------------------
__global__ __launch_bounds__(1024) void attn_k(
    const unsigned short* __restrict__ Qb, const unsigned short* __restrict__ KVb,
    unsigned short* __restrict__ Fp)
{
    __shared__ alignas(16) unsigned short KL[16][1024];   // K rows; reused as feats
    __shared__ alignas(16) unsigned short VL[16][1024];
    const int t = threadIdx.x;
    const int lane = t & 63;
    const int wid = t >> 6;                       // 0..15
    const size_t row = (size_t)blockIdx.x * 16 + wid;
    const size_t base = row * 1024;
    const size_t bkv  = row * 2048;
    const int off = lane * 16;

    ushort8v q0 = *reinterpret_cast<const ushort8v*>(&Qb[base + off]);
    ushort8v q1 = *reinterpret_cast<const ushort8v*>(&Qb[base + off + 8]);
    float qf[16];
#pragma unroll
    for (int j = 0; j < 8; ++j) { qf[j] = bf2f(q0[j]); qf[8 + j] = bf2f(q1[j]); }

    *reinterpret_cast<ushort8v*>(&KL[wid][off])     = *reinterpret_cast<const ushort8v*>(&KVb[bkv + off]);
    *reinterpret_cast<ushort8v*>(&KL[wid][off + 8]) = *reinterpret_cast<const ushort8v*>(&KVb[bkv + off + 8]);
    *reinterpret_cast<ushort8v*>(&VL[wid][off])     = *reinterpret_cast<const ushort8v*>(&KVb[bkv + 1024 + off]);
    *reinterpret_cast<ushort8v*>(&VL[wid][off + 8]) = *reinterpret_cast<const ushort8v*>(&KVb[bkv + 1024 + off + 8]);
    __syncthreads();

    const int sub = lane & 3;
    float s[16];
#pragma unroll
    for (int g = 0; g < 16; ++g) {
        const ushort8v k0 = *reinterpret_cast<const ushort8v*>(&KL[wid][g * 64 + sub * 16]);
        const ushort8v k1 = *reinterpret_cast<const ushort8v*>(&KL[wid][g * 64 + sub * 16 + 8]);
        float acc = 0.f;
#pragma unroll
        for (int j = 0; j < 8; ++j)
            acc += qf[j] * bf2f(k0[j]) + qf[8 + j] * bf2f(k1[j]);
        s[g] = acc;
    }
#pragma unroll
    for (int m = 1; m <= 2; m <<= 1)
#pragma unroll
        for (int g = 0; g < 16; ++g)
            s[g] += __shfl_xor(s[g], m, 64);

    float mx = s[0];
#pragma unroll
    for (int g = 1; g < 16; ++g) mx = fmaxf(mx, s[g]);
    float p[16], denom = 0.f;
#pragma unroll
    for (int g = 0; g < 16; ++g) {
        p[g] = __expf((s[g] - mx) * 0.125f);
        denom += p[g];
    }
    float inv = 1.f / denom;

    float f[16];
#pragma unroll
    for (int j = 0; j < 16; ++j) f[j] = 0.f;
#pragma unroll
    for (int g = 0; g < 16; ++g) {
        float pg = p[g] * inv;
        const ushort8v v0 = *reinterpret_cast<const ushort8v*>(&VL[wid][g * 64 + sub * 16]);
        const ushort8v v1 = *reinterpret_cast<const ushort8v*>(&VL[wid][g * 64 + sub * 16 + 8]);
#pragma unroll
        for (int j = 0; j < 8; ++j) {
            f[j]     += pg * bf2f(v0[j]);
            f[8 + j] += pg * bf2f(v1[j]);
        }
    }
    ushort8v o0, o1;
#pragma unroll
    for (int j = 0; j < 8; ++j) { o0[j] = f2bf(f[j]); o1[j] = f2bf(f[8 + j]); }
    *reinterpret_cast<ushort8v*>(&KL[wid][off])     = o0;
    *reinterpret_cast<ushort8v*>(&KL[wid][off + 8]) = o1;
    __syncthreads();

    // cooperative packed write: block = f-stripe (p, f); 32KB total
    const int r0 = blockIdx.x * 16;
    const int pp = r0 >> 8;
    const int ff = (r0 >> 4) & 15;
    const int tt = t >> 5;          // tile 0..31
    const int kc = (t >> 3) & 3;    // k-chunk 0..3
    const int rp = t & 7;           // row pair 0..7
    unsigned short* db = &Fp[((size_t)(pp * 32 + tt) * 16 + ff) * 512 + kc * 128 + rp * 16];
    *reinterpret_cast<ushort8v*>(db)     = *reinterpret_cast<const ushort8v*>(&KL[rp * 2][tt * 32 + kc * 8]);
    *reinterpret_cast<ushort8v*>(db + 8) = *reinterpret_cast<const ushort8v*>(&KL[rp * 2 + 1][tt * 32 + kc * 8]);
}

// ---------------------------------------------------------------------------
extern "C" void kernel_launch(void* const* d_in, const int* in_sizes, int n_in,
                              void* d_out, int out_size, void* d_ws, size_t ws_size,
                              hipStream_t stream)
{
    (void)in_sizes; (void)n_in; (void)out_size; (void)ws_size;
    const float* latent = (const float*)d_in[0];
    const float* cond   = (const float*)d_in[1];
    const float* Wq     = (const float*)d_in[2];
    const float* Wk     = (const float*)d_in[3];
    const float* Wv     = (const float*)d_in[4];
    const float* Wout   = (const float*)d_in[5];
    const float* bout   = (const float*)d_in[6];
    float* out = (float*)d_out;

    char* ws = (char*)d_ws;
    const size_t MB = 1ull << 20;
    unsigned short* wqp  = (unsigned short*)(ws + 0 * MB);    // 2 MB packed Wq
    unsigned short* wkvp = (unsigned short*)(ws + 2 * MB);    // 4 MB packed [Wk;Wv]
    unsigned short* wop  = (unsigned short*)(ws + 6 * MB);    // 2 MB packed Wout
    unsigned short* Qb   = (unsigned short*)(ws + 8 * MB);    // 128 MB row-major Q
    unsigned short* KVb  = (unsigned short*)(ws + 136 * MB);  // 256 MB row-major fused K|V
    unsigned short* Lp   = (unsigned short*)(ws + 392 * MB);  // 128 MB packed latent; reused as packed feats
    unsigned short* Cp   = (unsigned short*)(ws + 520 * MB);  // 128 MB packed cond
    unsigned short* Fp   = Lp;                                // Lp dead after QKV GEMM

    // 1) all packs in one dispatch (8448 blocks)
    pack_all_k<<<8448, 256, 0, stream>>>(latent, cond, Wq, Wk, Wv, Wout,
                                         Lp, Cp, wqp, wkvp, wop);

    // 2) merged Q + KV projections (3072 blocks)
    gemm_qkv<<<3072, 512, 0, stream>>>(Lp, Cp, wqp, wkvp, Qb, KVb);

    // 3) attention: row-major Q/KV in, PACKED feats out (into Fp = Lp)
    attn_k<<<NB / 16, 1024, 0, stream>>>(Qb, KVb, Fp);

    // 4) output projection
    gemm_out<<<1024, 512, 0, stream>>>(Fp, wop, bout, out);
}